// Round 20
// baseline (90.994 us; speedup 1.0000x reference)
//
#include <hip/hip_runtime.h>
#include <hip/hip_bf16.h>

// Problem constants
#define NN 64
#define BB 256
#define DD 1792
#define KK 35
#define PP 10
#define DQ 448          // D / 4 (float4s per row)
#define GR 4            // rows per group
#define NGRP 28         // 16-lane groups per 448-thread block

// PROVEN (R2-R8): 4-step row_shr DPP chain, bound_ctrl:0.
// Leaves the 16-lane-group sum in lane 15 of each group.
__device__ __forceinline__ float group16_sum_dpp(float x) {
    asm("v_add_f32_dpp %0, %0, %0 row_shr:1 row_mask:0xf bank_mask:0xf bound_ctrl:0" : "+v"(x));
    asm("v_add_f32_dpp %0, %0, %0 row_shr:2 row_mask:0xf bank_mask:0xf bound_ctrl:0" : "+v"(x));
    asm("v_add_f32_dpp %0, %0, %0 row_shr:4 row_mask:0xf bank_mask:0xf bound_ctrl:0" : "+v"(x));
    asm("v_add_f32_dpp %0, %0, %0 row_shr:8 row_mask:0xf bank_mask:0xf bound_ctrl:0" : "+v"(x));
    return x;
}

// Opacity pin (R19): value becomes asm-produced -> no re-load rematerialization.
#define PIN4(v) asm volatile("" : "+v"(v.x), "+v"(v.y), "+v"(v.z), "+v"(v.w))
#define PIN1(s) asm volatile("" : "+v"(s))

// ---------------------------------------------------------------------------
// K1: Gf = gamma * W_net; sG[p] = sum(Gf[p]); zc[p] = dot(beta,Wnet[p]) + b_net[p]
// ---------------------------------------------------------------------------
__global__ void prep_gf(const float* __restrict__ gamma, const float* __restrict__ beta,
                        const float* __restrict__ Wnet, const float* __restrict__ bnet,
                        float* __restrict__ GF, float* __restrict__ SG, float* __restrict__ ZC) {
    const int p = blockIdx.x;
    const int tid = threadIdx.x;
    float sg = 0.f, sb = 0.f;
#pragma unroll
    for (int j = 0; j < 7; ++j) {
        int d = j * 256 + tid;
        float wv = Wnet[p * DD + d];
        float g = gamma[d] * wv;
        GF[p * DD + d] = g;
        sg += g;
        sb += beta[d] * wv;
    }
#pragma unroll
    for (int off = 32; off > 0; off >>= 1) {
        sg += __shfl_xor(sg, off);
        sb += __shfl_xor(sb, off);
    }
    __shared__ float rs[4][2];
    if ((tid & 63) == 0) { rs[tid >> 6][0] = sg; rs[tid >> 6][1] = sb; }
    __syncthreads();
    if (tid == 0) {
        float a = 0.f, c = 0.f;
#pragma unroll
        for (int w = 0; w < 4; ++w) { a += rs[w][0]; c += rs[w][1]; }
        SG[p] = a;
        ZC[p] = c + bnet[p];
    }
}

// ---------------------------------------------------------------------------
// K2: bank[b][r] = dot(task[b], Wtok[r]) + btok[r]; ptok[b][d] likewise.
// ---------------------------------------------------------------------------
__global__ void prep_bank(const float* __restrict__ task,
                          const float* __restrict__ Wtok, const float* __restrict__ btok,
                          const float* __restrict__ Wptok, const float* __restrict__ bptok,
                          float* __restrict__ bank, float* __restrict__ ptok) {
    __shared__ float ti[32 * KK];
    const int tid = threadIdx.x;
    const int b0 = blockIdx.y * 32;
    for (int i = tid; i < 32 * KK; i += 256) ti[i] = task[b0 * KK + i];

    const int r = blockIdx.x * 256 + tid;
    const bool isbank = (r < PP * DD);
    const int rr = isbank ? r : (r - PP * DD);
    const float* __restrict__ W = isbank ? Wtok : Wptok;
    const float bias = isbank ? btok[r] : bptok[rr];

    float w[KK];
#pragma unroll
    for (int k = 0; k < KK; ++k) w[k] = W[rr * KK + k];

    __syncthreads();
#pragma unroll 1
    for (int bb = 0; bb < 32; ++bb) {
        float acc = bias;
#pragma unroll
        for (int k = 0; k < KK; ++k) acc = fmaf(ti[bb * KK + k], w[k], acc);
        const int b = b0 + bb;
        if (isbank) bank[b * (PP * DD) + r] = acc;
        else        ptok[b * DD + rr]       = acc;
    }
}

// ---------------------------------------------------------------------------
// K3 (fused_lds): 512 blocks = 2/CU (LDS 62.9 KB), each (b = bid&255,
// half = bid>>8) owns 32 rows as 8 groups of GR=4. X staged via
// global_load_lds (no dest VGPRs) double-buffered; counted vmcnt(8) leaves
// stores(4)+stage(4) in flight -> stores NEVER force-drained (epilogue
// vmcnt(4)). gf/bk/ptk pinned in VGPRs. Two raw lgkm-only barriers/group.
// ---------------------------------------------------------------------------
__global__ __launch_bounds__(448) void fused_lds(
    const float* __restrict__ X, const float* __restrict__ BANK,
    const float* __restrict__ PTOK, const float* __restrict__ GF,
    const float* __restrict__ SG, const float* __restrict__ ZC,
    float* __restrict__ OUT) {
    const int tid  = threadIdx.x;
    const int lane = tid & 63;
    const int c    = tid >> 6;          // chunk 0..6
    const int b    = blockIdx.x & (BB - 1);
    const int half = blockIdx.x >> 8;   // 0 or 1
    const int n0   = half * 32;

    const float4* __restrict__ X4 = (const float4*)X;
    const float4* __restrict__ B4 = (const float4*)BANK;
    const float4* __restrict__ G4 = (const float4*)GF;
    const float4* __restrict__ P4 = (const float4*)PTOK;
    float4* __restrict__ O4 = (float4*)OUT;

    __shared__ float xbuf[2][GR][DD];     // 57344 B
    __shared__ float red[GR][NGRP][12];   //  5376 B
    __shared__ float wlds[GR][PP];        //   160 B

    const size_t rstride = (size_t)BB * DQ;
    const size_t gbase = (size_t)b * DQ + c * 64 + lane;

#define STAGE(BUF, GN)                                                             \
    {                                                                              \
        _Pragma("unroll")                                                          \
        for (int r = 0; r < GR; ++r) {                                             \
            const float4* src = X4 + (size_t)(n0 + (GN) * GR + r) * rstride + gbase;\
            __builtin_amdgcn_global_load_lds(                                      \
                (const __attribute__((address_space(1))) void*)src,                \
                (__attribute__((address_space(3))) void*)&xbuf[BUF][r][c * 256],   \
                16, 0, 0);                                                         \
        }                                                                          \
        __builtin_amdgcn_sched_barrier(0);                                         \
    }

    // ---- stage group 0 first (HBM starts flowing immediately) ----
    STAGE(0, 0)

    // ---- persistent register state, then PIN it ----
    float4 ptk = P4[gbase];
    float4 gf[PP];
#pragma unroll
    for (int p = 0; p < PP; ++p) gf[p] = G4[(size_t)p * DQ + c * 64 + lane];
    float4 bk[PP];
#pragma unroll
    for (int p = 0; p < PP; ++p) bk[p] = B4[((size_t)b * PP + p) * DQ + c * 64 + lane];
    const int vv = tid & 15;
    float sgv = 0.f, zcv = 0.f;
    if (tid < GR * 16 && vv >= 2 && vv < 12) { sgv = SG[vv - 2]; zcv = ZC[vv - 2]; }

    PIN4(ptk);
#pragma unroll
    for (int p = 0; p < PP; ++p) { PIN4(gf[p]); PIN4(bk[p]); }
    PIN1(sgv); PIN1(zcv);

    const bool writer = ((lane & 15) == 15);
    const int g16 = tid >> 4;

#pragma unroll 1
    for (int g = 0; g < 8; ++g) {
        // ---- stage next group (async, no dest regs) ----
        if (g < 7) STAGE((g + 1) & 1, g + 1)

        // ---- counted wait: leaves stores(GR)+stage(GR) outstanding;
        //      guarantees stage(g) complete (it is older). Epilogue: only
        //      stores remain -> vmcnt(4). Never drains stores mid-loop. ----
        if (g < 7) { asm volatile("s_waitcnt vmcnt(8)" ::: "memory"); }
        else       { asm volatile("s_waitcnt vmcnt(4)" ::: "memory"); }
        __builtin_amdgcn_sched_barrier(0);

        const int cur = g & 1;

        // ---- phase 1: from LDS + pinned gf ----
#pragma unroll
        for (int r = 0; r < GR; ++r) {
            const float4 x = *(const float4*)&xbuf[cur][r][c * 256 + lane * 4];
            float4 t;
            t.x = x.x + ptk.x; t.y = x.y + ptk.y;
            t.z = x.z + ptk.z; t.w = x.w + ptk.w;

            float s1 = t.x + t.y + t.z + t.w;
            float s2 = t.x * t.x;
            s2 = fmaf(t.y, t.y, s2); s2 = fmaf(t.z, t.z, s2); s2 = fmaf(t.w, t.w, s2);
            float a[PP];
#pragma unroll
            for (int p = 0; p < PP; ++p) {
                float v = t.x * gf[p].x;
                v = fmaf(t.y, gf[p].y, v);
                v = fmaf(t.z, gf[p].z, v);
                v = fmaf(t.w, gf[p].w, v);
                a[p] = v;
            }
            s1 = group16_sum_dpp(s1);
            s2 = group16_sum_dpp(s2);
#pragma unroll
            for (int p = 0; p < PP; ++p) a[p] = group16_sum_dpp(a[p]);

            if (writer) {
                float4* dst = (float4*)&red[r][g16][0];
                dst[0] = make_float4(s1, s2, a[0], a[1]);
                dst[1] = make_float4(a[2], a[3], a[4], a[5]);
                dst[2] = make_float4(a[6], a[7], a[8], a[9]);
            }
        }

        // ---- raw barrier #1 (lgkm only — staged loads/stores in flight) ----
        asm volatile("s_waitcnt lgkmcnt(0)" ::: "memory");
        __builtin_amdgcn_sched_barrier(0);
        __builtin_amdgcn_s_barrier();
        __builtin_amdgcn_sched_barrier(0);

        // ---- finalize GR rows (first 64 threads; pinned SG/ZC) ----
        if (tid < GR * 16) {
            const int row = tid >> 4;
            float f = 0.f;
            if (vv < 12) {
#pragma unroll
                for (int q = 0; q < NGRP; ++q) f += red[row][q][vv];
            }
            const int bse = (tid & 63) & ~15;
            const float mu = __shfl(f, bse)     * (1.0f / (float)DD);
            const float ms = __shfl(f, bse + 1) * (1.0f / (float)DD);
            const float istd = rsqrtf(ms - mu * mu + 1e-5f);
            if (vv >= 2 && vv < 12) {
                const float z = istd * (f - mu * sgv) + zcv;
                wlds[row][vv - 2] = 1.0f / (1.0f + __expf(-z));
            }
        }

        // ---- raw barrier #2 ----
        asm volatile("s_waitcnt lgkmcnt(0)" ::: "memory");
        __builtin_amdgcn_sched_barrier(0);
        __builtin_amdgcn_s_barrier();
        __builtin_amdgcn_sched_barrier(0);

        // ---- phase 2: out = x(LDS) + w @ bank(pinned regs) ----
#pragma unroll
        for (int r = 0; r < GR; ++r) {
            const float4 x = *(const float4*)&xbuf[cur][r][c * 256 + lane * 4];
            float4 acc = x;
#pragma unroll
            for (int p = 0; p < PP; ++p) {
                const float wv = wlds[r][p];
                acc.x = fmaf(wv, bk[p].x, acc.x);
                acc.y = fmaf(wv, bk[p].y, acc.y);
                acc.z = fmaf(wv, bk[p].z, acc.z);
                acc.w = fmaf(wv, bk[p].w, acc.w);
            }
            O4[(size_t)(n0 + g * GR + r) * rstride + gbase] = acc;
        }
    }
#undef STAGE
}

// ---------------------------------------------------------------------------
extern "C" void kernel_launch(void* const* d_in, const int* in_sizes, int n_in,
                              void* d_out, int out_size, void* d_ws, size_t ws_size,
                              hipStream_t stream) {
    const float* X     = (const float*)d_in[0];
    const float* task  = (const float*)d_in[1];
    const float* Wtok  = (const float*)d_in[2];
    const float* btok  = (const float*)d_in[3];
    const float* Wptok = (const float*)d_in[4];
    const float* bptok = (const float*)d_in[5];
    const float* gamma = (const float*)d_in[6];
    const float* beta  = (const float*)d_in[7];
    const float* Wnet  = (const float*)d_in[8];
    const float* bnet  = (const float*)d_in[9];
    float* out = (float*)d_out;

    float* ws = (float*)d_ws;
    float* bank = ws;                                  // B*P*D = 4,587,520
    float* ptok = bank + (size_t)BB * PP * DD;         // B*D   =   458,752
    float* GF   = ptok + (size_t)BB * DD;              // P*D   =    17,920
    float* SG   = GF + PP * DD;                        // P
    float* ZC   = SG + PP;                             // P

    prep_gf<<<PP, 256, 0, stream>>>(gamma, beta, Wnet, bnet, GF, SG, ZC);
    prep_bank<<<dim3(77, 8), 256, 0, stream>>>(task, Wtok, btok, Wptok, bptok, bank, ptok);
    fused_lds<<<2 * BB, 448, 0, stream>>>(X, bank, ptok, GF, SG, ZC, out);
}

// Round 21
// 73.866 us; speedup vs baseline: 1.2319x; 1.2319x over previous
//
#include <hip/hip_runtime.h>
#include <hip/hip_bf16.h>

// Problem constants
#define NN 64
#define BB 256
#define DD 1792
#define KK 35
#define PP 10
#define DQ 448          // D / 4 (float4s per row)
#define GR 8            // rows per group
#define NGRP 28         // 16-lane groups per 448-thread block

typedef float fx4 __attribute__((ext_vector_type(4)));

// PROVEN (R2-R8): 4-step row_shr DPP chain, bound_ctrl:0.
// Leaves the 16-lane-group sum in lane 15 of each group.
__device__ __forceinline__ float group16_sum_dpp(float x) {
    asm("v_add_f32_dpp %0, %0, %0 row_shr:1 row_mask:0xf bank_mask:0xf bound_ctrl:0" : "+v"(x));
    asm("v_add_f32_dpp %0, %0, %0 row_shr:2 row_mask:0xf bank_mask:0xf bound_ctrl:0" : "+v"(x));
    asm("v_add_f32_dpp %0, %0, %0 row_shr:4 row_mask:0xf bank_mask:0xf bound_ctrl:0" : "+v"(x));
    asm("v_add_f32_dpp %0, %0, %0 row_shr:8 row_mask:0xf bank_mask:0xf bound_ctrl:0" : "+v"(x));
    return x;
}

// ---------------------------------------------------------------------------
// K1: Gf = gamma * W_net; sG[p] = sum(Gf[p]); zc[p] = dot(beta,Wnet[p]) + b_net[p]
// ---------------------------------------------------------------------------
__global__ void prep_gf(const float* __restrict__ gamma, const float* __restrict__ beta,
                        const float* __restrict__ Wnet, const float* __restrict__ bnet,
                        float* __restrict__ GF, float* __restrict__ SG, float* __restrict__ ZC) {
    const int p = blockIdx.x;
    const int tid = threadIdx.x;
    float sg = 0.f, sb = 0.f;
#pragma unroll
    for (int j = 0; j < 7; ++j) {
        int d = j * 256 + tid;
        float wv = Wnet[p * DD + d];
        float g = gamma[d] * wv;
        GF[p * DD + d] = g;
        sg += g;
        sb += beta[d] * wv;
    }
#pragma unroll
    for (int off = 32; off > 0; off >>= 1) {
        sg += __shfl_xor(sg, off);
        sb += __shfl_xor(sb, off);
    }
    __shared__ float rs[4][2];
    if ((tid & 63) == 0) { rs[tid >> 6][0] = sg; rs[tid >> 6][1] = sb; }
    __syncthreads();
    if (tid == 0) {
        float a = 0.f, c = 0.f;
#pragma unroll
        for (int w = 0; w < 4; ++w) { a += rs[w][0]; c += rs[w][1]; }
        SG[p] = a;
        ZC[p] = c + bnet[p];
    }
}

// ---------------------------------------------------------------------------
// K2: bank[b][r] = dot(task[b], Wtok[r]) + btok[r]; ptok[b][d] likewise.
// ---------------------------------------------------------------------------
__global__ void prep_bank(const float* __restrict__ task,
                          const float* __restrict__ Wtok, const float* __restrict__ btok,
                          const float* __restrict__ Wptok, const float* __restrict__ bptok,
                          float* __restrict__ bank, float* __restrict__ ptok) {
    __shared__ float ti[32 * KK];
    const int tid = threadIdx.x;
    const int b0 = blockIdx.y * 32;
    for (int i = tid; i < 32 * KK; i += 256) ti[i] = task[b0 * KK + i];

    const int r = blockIdx.x * 256 + tid;
    const bool isbank = (r < PP * DD);
    const int rr = isbank ? r : (r - PP * DD);
    const float* __restrict__ W = isbank ? Wtok : Wptok;
    const float bias = isbank ? btok[r] : bptok[rr];

    float w[KK];
#pragma unroll
    for (int k = 0; k < KK; ++k) w[k] = W[rr * KK + k];

    __syncthreads();
#pragma unroll 1
    for (int bb = 0; bb < 32; ++bb) {
        float acc = bias;
#pragma unroll
        for (int k = 0; k < KK; ++k) acc = fmaf(ti[bb * KK + k], w[k], acc);
        const int b = b0 + bb;
        if (isbank) bank[b * (PP * DD) + r] = acc;
        else        ptok[b * DD + rr]       = acc;
    }
}

// ---------------------------------------------------------------------------
// K3 (fused_pipe): ONE block per b (256 blocks). 448 threads. R17 structure
// (best known: 74.3 us) with ONE change: nontemporal out-stores, so the
// 117 MB of output writes stop allocating in L3 and evicting X. X+bank
// (135 MB) then fits L3 fully -> X re-reads become L3 hits across replays.
//   BURST(g+1) -> PHASE1(g) -> BARRIER -> { FINALIZE(g) ; PHASE2(g-1) }
// ---------------------------------------------------------------------------
__global__ __launch_bounds__(448, 1) void fused_pipe(
    const float* __restrict__ X, const float* __restrict__ BANK,
    const float* __restrict__ PTOK, const float* __restrict__ GF,
    const float* __restrict__ SG, const float* __restrict__ ZC,
    float* __restrict__ OUT) {
    const int tid = threadIdx.x;
    const int b = blockIdx.x;

    const float4* __restrict__ X4 = (const float4*)X;
    const float4* __restrict__ B4 = (const float4*)BANK;
    const float4* __restrict__ G4 = (const float4*)GF;
    const float4* __restrict__ P4 = (const float4*)PTOK;
    fx4* __restrict__ OO = (fx4*)OUT;

    __shared__ float red[2][GR][NGRP][12];   // 21504 B
    __shared__ float wlds[2][GR][PP];        //   640 B

    // ---- persistent state: loaded once for the whole block ----
    const float4 ptk = P4[(size_t)b * DQ + tid];
    float4 gf[PP];
#pragma unroll
    for (int p = 0; p < PP; ++p) gf[p] = G4[(size_t)p * DQ + tid];
    float4 bk[PP];
#pragma unroll
    for (int p = 0; p < PP; ++p) bk[p] = B4[((size_t)b * PP + p) * DQ + tid];

    const bool writer = ((tid & 15) == 15);
    const int g16 = tid >> 4;

    float4 x0[GR], x1[GR], x2[GR];

#define BURST(XN, GN)                                                              \
    {                                                                              \
        _Pragma("unroll")                                                          \
        for (int r = 0; r < GR; ++r)                                               \
            XN[r] = X4[((size_t)((GN) * GR + r) * BB + b) * DQ + tid];             \
        __builtin_amdgcn_sched_barrier(0);                                         \
    }

#define BARRIER_RAW()                                                              \
    asm volatile("s_waitcnt lgkmcnt(0)" ::: "memory");                             \
    __builtin_amdgcn_sched_barrier(0);                                             \
    __builtin_amdgcn_s_barrier();                                                  \
    __builtin_amdgcn_sched_barrier(0);

#define PHASE1(XC, RB)                                                             \
    {                                                                              \
        _Pragma("unroll")                                                          \
        for (int r = 0; r < GR; ++r) {                                             \
            float4 t;                                                              \
            t.x = XC[r].x + ptk.x; t.y = XC[r].y + ptk.y;                          \
            t.z = XC[r].z + ptk.z; t.w = XC[r].w + ptk.w;                          \
            float s1 = t.x + t.y + t.z + t.w;                                      \
            float s2 = t.x * t.x;                                                  \
            s2 = fmaf(t.y, t.y, s2); s2 = fmaf(t.z, t.z, s2);                      \
            s2 = fmaf(t.w, t.w, s2);                                               \
            float a[PP];                                                           \
            _Pragma("unroll")                                                      \
            for (int p = 0; p < PP; ++p) {                                         \
                float v = t.x * gf[p].x;                                           \
                v = fmaf(t.y, gf[p].y, v);                                         \
                v = fmaf(t.z, gf[p].z, v);                                         \
                v = fmaf(t.w, gf[p].w, v);                                         \
                a[p] = v;                                                          \
            }                                                                      \
            s1 = group16_sum_dpp(s1);                                              \
            s2 = group16_sum_dpp(s2);                                              \
            _Pragma("unroll")                                                      \
            for (int p = 0; p < PP; ++p) a[p] = group16_sum_dpp(a[p]);             \
            if (writer) {                                                          \
                float4* dst = (float4*)&red[RB][r][g16][0];                        \
                dst[0] = make_float4(s1, s2, a[0], a[1]);                          \
                dst[1] = make_float4(a[2], a[3], a[4], a[5]);                      \
                dst[2] = make_float4(a[6], a[7], a[8], a[9]);                      \
            }                                                                      \
        }                                                                          \
    }

#define FINALIZE(RB)                                                               \
    if (tid < GR * 16) {                                                           \
        const int row = tid >> 4;                                                  \
        const int v = tid & 15;                                                    \
        float f = 0.f;                                                             \
        if (v < 12) {                                                              \
            _Pragma("unroll")                                                      \
            for (int q = 0; q < NGRP; ++q) f += red[RB][row][q][v];                \
        }                                                                          \
        const int bse = (tid & 63) & ~15;                                          \
        const float mu = __shfl(f, bse)     * (1.0f / (float)DD);                  \
        const float ms = __shfl(f, bse + 1) * (1.0f / (float)DD);                  \
        const float istd = rsqrtf(ms - mu * mu + 1e-5f);                           \
        if (v >= 2 && v < 12) {                                                    \
            const int p = v - 2;                                                   \
            const float z = istd * (f - mu * SG[p]) + ZC[p];                       \
            wlds[RB][row][p] = 1.0f / (1.0f + __expf(-z));                         \
        }                                                                          \
    }

#define PHASE2(XC, WB, GN)                                                         \
    {                                                                              \
        _Pragma("unroll")                                                          \
        for (int r = 0; r < GR; ++r) {                                             \
            float4 acc = XC[r];                                                    \
            _Pragma("unroll")                                                      \
            for (int p = 0; p < PP; ++p) {                                         \
                const float wv = wlds[WB][r][p];                                   \
                acc.x = fmaf(wv, bk[p].x, acc.x);                                  \
                acc.y = fmaf(wv, bk[p].y, acc.y);                                  \
                acc.z = fmaf(wv, bk[p].z, acc.z);                                  \
                acc.w = fmaf(wv, bk[p].w, acc.w);                                  \
            }                                                                      \
            fx4 av; av.x = acc.x; av.y = acc.y; av.z = acc.z; av.w = acc.w;        \
            __builtin_nontemporal_store(av,                                        \
                &OO[((size_t)((GN) * GR + r) * BB + b) * DQ + tid]);               \
        }                                                                          \
    }

    // ---- prologue ----
    BURST(x0, 0)

    // g = 0
    BURST(x1, 1) PHASE1(x0, 0) BARRIER_RAW() FINALIZE(0)
    // g = 1
    BURST(x2, 2) PHASE1(x1, 1) BARRIER_RAW() FINALIZE(1) PHASE2(x0, 0, 0)
    // g = 2
    BURST(x0, 3) PHASE1(x2, 0) BARRIER_RAW() FINALIZE(0) PHASE2(x1, 1, 1)
    // g = 3
    BURST(x1, 4) PHASE1(x0, 1) BARRIER_RAW() FINALIZE(1) PHASE2(x2, 0, 2)
    // g = 4
    BURST(x2, 5) PHASE1(x1, 0) BARRIER_RAW() FINALIZE(0) PHASE2(x0, 1, 3)
    // g = 5
    BURST(x0, 6) PHASE1(x2, 1) BARRIER_RAW() FINALIZE(1) PHASE2(x1, 0, 4)
    // g = 6
    BURST(x1, 7) PHASE1(x0, 0) BARRIER_RAW() FINALIZE(0) PHASE2(x2, 1, 5)
    // g = 7
    PHASE1(x1, 1) BARRIER_RAW() FINALIZE(1) PHASE2(x0, 0, 6)
    // epilogue
    BARRIER_RAW() PHASE2(x1, 1, 7)

#undef PHASE2
#undef FINALIZE
#undef PHASE1
#undef BARRIER_RAW
#undef BURST
}

// ---------------------------------------------------------------------------
extern "C" void kernel_launch(void* const* d_in, const int* in_sizes, int n_in,
                              void* d_out, int out_size, void* d_ws, size_t ws_size,
                              hipStream_t stream) {
    const float* X     = (const float*)d_in[0];
    const float* task  = (const float*)d_in[1];
    const float* Wtok  = (const float*)d_in[2];
    const float* btok  = (const float*)d_in[3];
    const float* Wptok = (const float*)d_in[4];
    const float* bptok = (const float*)d_in[5];
    const float* gamma = (const float*)d_in[6];
    const float* beta  = (const float*)d_in[7];
    const float* Wnet  = (const float*)d_in[8];
    const float* bnet  = (const float*)d_in[9];
    float* out = (float*)d_out;

    float* ws = (float*)d_ws;
    float* bank = ws;                                  // B*P*D = 4,587,520
    float* ptok = bank + (size_t)BB * PP * DD;         // B*D   =   458,752
    float* GF   = ptok + (size_t)BB * DD;              // P*D   =    17,920
    float* SG   = GF + PP * DD;                        // P
    float* ZC   = SG + PP;                             // P

    prep_gf<<<PP, 256, 0, stream>>>(gamma, beta, Wnet, bnet, GF, SG, ZC);
    prep_bank<<<dim3(77, 8), 256, 0, stream>>>(task, Wtok, btok, Wptok, bptok, bank, ptok);
    fused_pipe<<<BB, 448, 0, stream>>>(X, bank, ptok, GF, SG, ZC, out);
}